// Round 1
// baseline (354.905 us; speedup 1.0000x reference)
//
#include <hip/hip_runtime.h>
#include <math.h>

#define D_MODEL 96
#define D_STATE 16
#define IMG 32
#define NUM_V 5
#define GROUPS 4
#define BATCH 4
#define HW (IMG*IMG)                    // 1024
#define CPG (D_MODEL/GROUPS)            // 24
#define NCOEF (D_MODEL + 2*D_STATE)     // 128 channels: [0,96)=delta, [96,112)=B, [112,128)=C
#define Y_SIZE (BATCH*NUM_V*D_MODEL*HW) // 1966080

// ---------------- GroupNorm: compute u_norm into ws ----------------
__global__ __launch_bounds__(256) void gn_kernel(const float* __restrict__ u,
                                                 const float* __restrict__ gamma,
                                                 const float* __restrict__ beta,
                                                 float* __restrict__ unorm) {
    int b = blockIdx.x >> 2, g = blockIdx.x & 3;
    int t = threadIdx.x;
    const int base = (b * D_MODEL + g * CPG) * HW;
    const int n = CPG * HW;  // 24576
    float s = 0.f, s2 = 0.f;
    for (int k = t; k < n; k += 256) {
        float v = u[base + k];
        s += v;
        s2 = fmaf(v, v, s2);
    }
    // wave64 reduce
    for (int off = 32; off; off >>= 1) {
        s  += __shfl_down(s,  off);
        s2 += __shfl_down(s2, off);
    }
    __shared__ float red[8];
    int wid = t >> 6;
    if ((t & 63) == 0) { red[wid * 2] = s; red[wid * 2 + 1] = s2; }
    __syncthreads();
    if (t == 0) {
        float S = 0.f, S2 = 0.f;
        for (int i = 0; i < 4; ++i) { S += red[i * 2]; S2 += red[i * 2 + 1]; }
        float mu  = S / (float)n;
        float var = S2 / (float)n - mu * mu;
        red[0] = mu;
        red[1] = rsqrtf(var + 1e-5f);
    }
    __syncthreads();
    float mu = red[0], rs = red[1];
    for (int k = t; k < n; k += 256) {
        int c = g * CPG + (k >> 10);
        unorm[base + k] = (u[base + k] - mu) * rs * gamma[c] + beta[c];
    }
}

// ---------------- circular 3x3 convs: delta (softplus+clip), B_val, C_val ----------------
// block-uniform oc -> scalar weight loads; +-1 column taps via intra-row shuffles
__global__ __launch_bounds__(256) void conv_kernel(const float* __restrict__ unorm,
                                                   const float* __restrict__ w_delta,
                                                   const float* __restrict__ b_delta,
                                                   const float* __restrict__ w_B,
                                                   const float* __restrict__ w_C,
                                                   const float* __restrict__ dt_ptr,
                                                   float* __restrict__ coef) {
    int bid = blockIdx.x;
    int b  = bid >> 9;            // 512 blocks per batch
    int oc = (bid >> 2) & 127;
    int hq = bid & 3;
    int t  = threadIdx.x;
    int h  = hq * 8 + (t >> 5);
    int w  = t & 31;
    int lane    = t & 63;
    int rowBase = lane & 32;
    int lsrc = rowBase | ((lane + 31) & 31);  // holds value at w-1
    int rsrc = rowBase | ((lane + 1) & 31);   // holds value at w+1

    const float* wp;
    float bias;
    bool is_delta = false;
    if (oc < D_MODEL) {
        wp = w_delta + oc * D_MODEL * 9;
        bias = b_delta[oc] + dt_ptr[0];
        is_delta = true;
    } else if (oc < D_MODEL + D_STATE) {
        wp = w_B + (oc - D_MODEL) * D_MODEL * 9;
        bias = 0.f;
    } else {
        wp = w_C + (oc - D_MODEL - D_STATE) * D_MODEL * 9;
        bias = 0.f;
    }
    const float* ub = unorm + b * D_MODEL * HW;

    float acc = bias;
    for (int ic = 0; ic < D_MODEL; ++ic) {
        const float* wr = wp + ic * 9;
        const float* ur = ub + ic * HW;
        #pragma unroll
        for (int kh = 0; kh < 3; ++kh) {
            int hh = (h + kh + 31) & 31;
            float c = ur[hh * 32 + w];
            float l = __shfl(c, lsrc);
            float r = __shfl(c, rsrc);
            acc = fmaf(wr[kh * 3 + 0], l, acc);
            acc = fmaf(wr[kh * 3 + 1], c, acc);
            acc = fmaf(wr[kh * 3 + 2], r, acc);
        }
    }
    if (is_delta) {
        float sp = acc > 20.f ? acc : log1pf(__expf(acc));
        acc = fminf(fmaxf(sp, 1e-4f), 5.f);
    }
    coef[(b * NCOEF + oc) * HW + h * 32 + w] = acc;
}

// ---------------- state update: s_new + y_out (memory-bound) ----------------
__global__ __launch_bounds__(256) void state_kernel(const float* __restrict__ u_t,
                                                    const float* __restrict__ s_prev,
                                                    const float* __restrict__ coef,
                                                    const float* __restrict__ log_A,
                                                    const float* __restrict__ D_param,
                                                    float* __restrict__ out) {
    int gid = blockIdx.x * 256 + threadIdx.x;
    int b  = gid / (D_MODEL * HW);
    int r  = gid - b * (D_MODEL * HW);
    int d  = r >> 10;
    int hw = r & 1023;
    int h = hw >> 5, w = hw & 31;

    float delta = coef[(b * NCOEF + d) * HW + hw];
    float u     = u_t[(b * D_MODEL + d) * HW + hw];
    float Dp    = D_param[d];

    float Ab[D_STATE], bu[D_STATE], Cv[D_STATE];
    #pragma unroll
    for (int n = 0; n < D_STATE; ++n) {
        float Bv = coef[(b * NCOEF + D_MODEL + n) * HW + hw];
        Cv[n]    = coef[(b * NCOEF + D_MODEL + D_STATE + n) * HW + hw];
        float A  = -__expf(log_A[d * D_STATE + n]);
        Ab[n]    = __expf(delta * A);
        bu[n]    = delta * Bv * u;
    }

    float* out_s = out + Y_SIZE;
    const int vh[NUM_V] = {0, 0, 0, 1, -1};
    const int vw[NUM_V] = {0, 1, -1, 0, 0};
    #pragma unroll
    for (int i = 0; i < NUM_V; ++i) {
        int hs  = (h - vh[i]) & 31;
        int ws  = (w - vw[i]) & 31;
        int hw2 = hs * 32 + ws;
        long sbase = (long)((b * NUM_V + i) * D_MODEL + d) * (D_STATE * HW);
        float y = 0.f;
        #pragma unroll
        for (int n = 0; n < D_STATE; ++n) {
            float s  = s_prev[sbase + n * HW + hw2];
            float sn = fmaf(Ab[n], s, bu[n]);
            out_s[sbase + n * HW + hw] = sn;
            y = fmaf(sn, Cv[n], y);
        }
        out[(long)((b * NUM_V + i) * D_MODEL + d) * HW + hw] = y + u * Dp;
    }
}

extern "C" void kernel_launch(void* const* d_in, const int* in_sizes, int n_in,
                              void* d_out, int out_size, void* d_ws, size_t ws_size,
                              hipStream_t stream) {
    const float* u_t     = (const float*)d_in[0];
    const float* s_prev  = (const float*)d_in[1];
    const float* gamma   = (const float*)d_in[2];
    const float* beta    = (const float*)d_in[3];
    const float* w_delta = (const float*)d_in[4];
    const float* b_delta = (const float*)d_in[5];
    const float* w_B     = (const float*)d_in[6];
    const float* w_C     = (const float*)d_in[7];
    const float* log_A   = (const float*)d_in[8];
    const float* D_param = (const float*)d_in[9];
    const float* dt_ptr  = (const float*)d_in[10];
    float* out = (float*)d_out;

    float* unorm = (float*)d_ws;                       // BATCH*96*1024 floats
    float* coef  = unorm + BATCH * D_MODEL * HW;       // BATCH*128*1024 floats

    hipLaunchKernelGGL(gn_kernel, dim3(BATCH * GROUPS), dim3(256), 0, stream,
                       u_t, gamma, beta, unorm);
    hipLaunchKernelGGL(conv_kernel, dim3(BATCH * NCOEF * 4), dim3(256), 0, stream,
                       unorm, w_delta, b_delta, w_B, w_C, dt_ptr, coef);
    hipLaunchKernelGGL(state_kernel, dim3(BATCH * D_MODEL * HW / 256), dim3(256), 0, stream,
                       u_t, s_prev, coef, log_A, D_param, out);
}

// Round 4
// 310.197 us; speedup vs baseline: 1.1441x; 1.1441x over previous
//
#include <hip/hip_runtime.h>
#include <math.h>

#define D_MODEL 96
#define D_STATE 16
#define IMG 32
#define NUM_V 5
#define GROUPS 4
#define BATCH 4
#define HW (IMG*IMG)                    // 1024
#define CPG (D_MODEL/GROUPS)            // 24
#define NCOEF (D_MODEL + 2*D_STATE)     // 128: [0,96)=delta, [96,112)=B, [112,128)=C
#define Y_SIZE (BATCH*NUM_V*D_MODEL*HW) // 1966080

typedef float f32x4 __attribute__((ext_vector_type(4)));

__device__ __forceinline__ void nt_store4(const float4& v, float4* p) {
    f32x4 tmp = {v.x, v.y, v.z, v.w};
    __builtin_nontemporal_store(tmp, (f32x4*)p);
}

// ---------------- GroupNorm (float4) ----------------
__global__ __launch_bounds__(256) void gn_kernel(const float4* __restrict__ u4,
                                                 const float* __restrict__ gamma,
                                                 const float* __restrict__ beta,
                                                 float4* __restrict__ unorm4) {
    int b = blockIdx.x >> 2, g = blockIdx.x & 3;
    int t = threadIdx.x;
    const int base4 = ((b * D_MODEL + g * CPG) * HW) >> 2;
    const int n4 = (CPG * HW) >> 2;  // 6144 float4s
    float s = 0.f, s2 = 0.f;
    for (int k = t; k < n4; k += 256) {
        float4 v = u4[base4 + k];
        s += v.x + v.y + v.z + v.w;
        s2 = fmaf(v.x, v.x, fmaf(v.y, v.y, fmaf(v.z, v.z, fmaf(v.w, v.w, s2))));
    }
    for (int off = 32; off; off >>= 1) {
        s  += __shfl_down(s,  off);
        s2 += __shfl_down(s2, off);
    }
    __shared__ float red[8];
    int wid = t >> 6;
    if ((t & 63) == 0) { red[wid * 2] = s; red[wid * 2 + 1] = s2; }
    __syncthreads();
    if (t == 0) {
        float S = 0.f, S2 = 0.f;
        for (int i = 0; i < 4; ++i) { S += red[i * 2]; S2 += red[i * 2 + 1]; }
        float nf = (float)(CPG * HW);
        float mu  = S / nf;
        float var = S2 / nf - mu * mu;
        red[0] = mu;
        red[1] = rsqrtf(var + 1e-5f);
    }
    __syncthreads();
    float mu = red[0], rs = red[1];
    for (int k = t; k < n4; k += 256) {
        int c = g * CPG + (k >> 8);           // 256 float4 per channel
        float ga = gamma[c] * rs, be = beta[c] - mu * gamma[c] * rs;
        float4 v = u4[base4 + k];
        float4 o;
        o.x = fmaf(v.x, ga, be); o.y = fmaf(v.y, ga, be);
        o.z = fmaf(v.z, ga, be); o.w = fmaf(v.w, ga, be);
        unorm4[base4 + k] = o;
    }
}

// ---------------- circular 3x3 convs (float4, 4 pixels/thread) ----------------
__global__ __launch_bounds__(256) void conv_kernel(const float4* __restrict__ unorm4,
                                                   const float* __restrict__ w_delta,
                                                   const float* __restrict__ b_delta,
                                                   const float* __restrict__ w_B,
                                                   const float* __restrict__ w_C,
                                                   const float* __restrict__ dt_ptr,
                                                   float4* __restrict__ coef4) {
    int bid = blockIdx.x;             // 512 = BATCH * NCOEF
    int b  = bid >> 7;
    int oc = bid & 127;
    int t  = threadIdx.x;
    int h  = t >> 3;                  // 0..31
    int j  = t & 7;                   // quad index in row
    int lane = t & 63;
    int ll = (lane & 56) | ((j + 7) & 7);
    int rl = (lane & 56) | ((j + 1) & 7);

    const float* wp;
    float bias;
    bool is_delta = false;
    if (oc < D_MODEL) {
        wp = w_delta + oc * D_MODEL * 9;
        bias = b_delta[oc] + dt_ptr[0];
        is_delta = true;
    } else if (oc < D_MODEL + D_STATE) {
        wp = w_B + (oc - D_MODEL) * D_MODEL * 9;
        bias = 0.f;
    } else {
        wp = w_C + (oc - D_MODEL - D_STATE) * D_MODEL * 9;
        bias = 0.f;
    }
    const float4* ub4 = unorm4 + ((b * D_MODEL * HW) >> 2);

    float4 acc = {bias, bias, bias, bias};
    int hm = (h + 31) & 31, hp = (h + 1) & 31;
    int ro[3] = {hm * 8 + j, h * 8 + j, hp * 8 + j};   // float4 row offsets

    for (int ic = 0; ic < D_MODEL; ++ic) {
        const float* wr = wp + ic * 9;
        const int icb = ic * 256;
        #pragma unroll
        for (int kh = 0; kh < 3; ++kh) {
            float4 q = ub4[icb + ro[kh]];
            float lw = __shfl(q.w, ll);
            float rx = __shfl(q.x, rl);
            float wa = wr[kh * 3 + 0], wb = wr[kh * 3 + 1], wc = wr[kh * 3 + 2];
            acc.x = fmaf(wa, lw,  fmaf(wb, q.x, fmaf(wc, q.y, acc.x)));
            acc.y = fmaf(wa, q.x, fmaf(wb, q.y, fmaf(wc, q.z, acc.y)));
            acc.z = fmaf(wa, q.y, fmaf(wb, q.z, fmaf(wc, q.w, acc.z)));
            acc.w = fmaf(wa, q.z, fmaf(wb, q.w, fmaf(wc, rx,  acc.w)));
        }
    }
    if (is_delta) {
        float* a = (float*)&acc;
        #pragma unroll
        for (int k = 0; k < 4; ++k) {
            float x = a[k];
            float sp = x > 20.f ? x : log1pf(__expf(x));
            a[k] = fminf(fmaxf(sp, 1e-4f), 5.f);
        }
    }
    coef4[((b * NCOEF + oc) * HW >> 2) + h * 8 + j] = acc;
}

// ---------------- state update (float4, memory-bound) ----------------
__global__ __launch_bounds__(128) void state_kernel(const float4* __restrict__ u4,
                                                    const float4* __restrict__ s_prev4,
                                                    const float4* __restrict__ coef4,
                                                    const float* __restrict__ log_A,
                                                    const float* __restrict__ D_param,
                                                    float4* __restrict__ out4) {
    int bid = blockIdx.x;               // 768
    int b = bid / 192;
    int r = bid - b * 192;
    int d = r >> 1;
    int half = r & 1;
    int t = threadIdx.x;
    int h = half * 16 + (t >> 3);       // 0..31
    int j = t & 7;
    int lane = t & 63;
    int ll = (lane & 56) | ((j + 7) & 7);
    int rl = (lane & 56) | ((j + 1) & 7);
    int hw4 = h * 8 + j;                // float4 offset within plane

    float4 delta = coef4[((b * NCOEF + d) * HW >> 2) + hw4];
    float4 u     = u4[((b * D_MODEL + d) * HW >> 2) + hw4];
    float Dp     = D_param[d];
    const float* lA = log_A + d * D_STATE;

    // per-direction s_prev plane bases (float4 units)
    int pb[NUM_V];
    #pragma unroll
    for (int i = 0; i < NUM_V; ++i)
        pb[i] = ((b * NUM_V + i) * D_MODEL + d) * (D_STATE * HW / 4);
    int hm4 = (((h + 31) & 31) * 8) + j;   // row h-1 (for vh=+1)
    int hp4 = (((h + 1) & 31) * 8) + j;    // row h+1 (for vh=-1)

    float4* outs4 = out4 + (Y_SIZE >> 2);

    float4 y0 = {0,0,0,0}, y1 = {0,0,0,0}, y2 = {0,0,0,0}, y3 = {0,0,0,0}, y4v = {0,0,0,0};

    #pragma unroll 2
    for (int n = 0; n < D_STATE; ++n) {
        int n4 = n * (HW / 4);
        float4 Bv = coef4[((b * NCOEF + D_MODEL + n) * HW >> 2) + hw4];
        float4 Cv = coef4[((b * NCOEF + D_MODEL + D_STATE + n) * HW >> 2) + hw4];
        float A = -__expf(lA[n]);
        float4 Ab, bu;
        Ab.x = __expf(delta.x * A); Ab.y = __expf(delta.y * A);
        Ab.z = __expf(delta.z * A); Ab.w = __expf(delta.w * A);
        bu.x = delta.x * Bv.x * u.x; bu.y = delta.y * Bv.y * u.y;
        bu.z = delta.z * Bv.z * u.z; bu.w = delta.w * Bv.w * u.w;

        // i=0: no shift
        {
            float4 s = s_prev4[pb[0] + n4 + hw4];
            float4 sn;
            sn.x = fmaf(Ab.x, s.x, bu.x); sn.y = fmaf(Ab.y, s.y, bu.y);
            sn.z = fmaf(Ab.z, s.z, bu.z); sn.w = fmaf(Ab.w, s.w, bu.w);
            nt_store4(sn, &outs4[pb[0] + n4 + hw4]);
            y0.x = fmaf(sn.x, Cv.x, y0.x); y0.y = fmaf(sn.y, Cv.y, y0.y);
            y0.z = fmaf(sn.z, Cv.z, y0.z); y0.w = fmaf(sn.w, Cv.w, y0.w);
        }
        // i=1: vw=+1 -> src col w-1
        {
            float4 q = s_prev4[pb[1] + n4 + hw4];
            float lw = __shfl(q.w, ll);
            float4 s = {lw, q.x, q.y, q.z};
            float4 sn;
            sn.x = fmaf(Ab.x, s.x, bu.x); sn.y = fmaf(Ab.y, s.y, bu.y);
            sn.z = fmaf(Ab.z, s.z, bu.z); sn.w = fmaf(Ab.w, s.w, bu.w);
            nt_store4(sn, &outs4[pb[1] + n4 + hw4]);
            y1.x = fmaf(sn.x, Cv.x, y1.x); y1.y = fmaf(sn.y, Cv.y, y1.y);
            y1.z = fmaf(sn.z, Cv.z, y1.z); y1.w = fmaf(sn.w, Cv.w, y1.w);
        }
        // i=2: vw=-1 -> src col w+1
        {
            float4 q = s_prev4[pb[2] + n4 + hw4];
            float rx = __shfl(q.x, rl);
            float4 s = {q.y, q.z, q.w, rx};
            float4 sn;
            sn.x = fmaf(Ab.x, s.x, bu.x); sn.y = fmaf(Ab.y, s.y, bu.y);
            sn.z = fmaf(Ab.z, s.z, bu.z); sn.w = fmaf(Ab.w, s.w, bu.w);
            nt_store4(sn, &outs4[pb[2] + n4 + hw4]);
            y2.x = fmaf(sn.x, Cv.x, y2.x); y2.y = fmaf(sn.y, Cv.y, y2.y);
            y2.z = fmaf(sn.z, Cv.z, y2.z); y2.w = fmaf(sn.w, Cv.w, y2.w);
        }
        // i=3: vh=+1 -> src row h-1
        {
            float4 s = s_prev4[pb[3] + n4 + hm4];
            float4 sn;
            sn.x = fmaf(Ab.x, s.x, bu.x); sn.y = fmaf(Ab.y, s.y, bu.y);
            sn.z = fmaf(Ab.z, s.z, bu.z); sn.w = fmaf(Ab.w, s.w, bu.w);
            nt_store4(sn, &outs4[pb[3] + n4 + hw4]);
            y3.x = fmaf(sn.x, Cv.x, y3.x); y3.y = fmaf(sn.y, Cv.y, y3.y);
            y3.z = fmaf(sn.z, Cv.z, y3.z); y3.w = fmaf(sn.w, Cv.w, y3.w);
        }
        // i=4: vh=-1 -> src row h+1
        {
            float4 s = s_prev4[pb[4] + n4 + hp4];
            float4 sn;
            sn.x = fmaf(Ab.x, s.x, bu.x); sn.y = fmaf(Ab.y, s.y, bu.y);
            sn.z = fmaf(Ab.z, s.z, bu.z); sn.w = fmaf(Ab.w, s.w, bu.w);
            nt_store4(sn, &outs4[pb[4] + n4 + hw4]);
            y4v.x = fmaf(sn.x, Cv.x, y4v.x); y4v.y = fmaf(sn.y, Cv.y, y4v.y);
            y4v.z = fmaf(sn.z, Cv.z, y4v.z); y4v.w = fmaf(sn.w, Cv.w, y4v.w);
        }
    }

    float4 du;
    du.x = u.x * Dp; du.y = u.y * Dp; du.z = u.z * Dp; du.w = u.w * Dp;
    float4* yy[NUM_V] = {&y0, &y1, &y2, &y3, &y4v};
    #pragma unroll
    for (int i = 0; i < NUM_V; ++i) {
        float4 o;
        o.x = yy[i]->x + du.x; o.y = yy[i]->y + du.y;
        o.z = yy[i]->z + du.z; o.w = yy[i]->w + du.w;
        out4[(((b * NUM_V + i) * D_MODEL + d) * HW >> 2) + hw4] = o;
    }
}

extern "C" void kernel_launch(void* const* d_in, const int* in_sizes, int n_in,
                              void* d_out, int out_size, void* d_ws, size_t ws_size,
                              hipStream_t stream) {
    const float* u_t     = (const float*)d_in[0];
    const float* s_prev  = (const float*)d_in[1];
    const float* gamma   = (const float*)d_in[2];
    const float* beta    = (const float*)d_in[3];
    const float* w_delta = (const float*)d_in[4];
    const float* b_delta = (const float*)d_in[5];
    const float* w_B     = (const float*)d_in[6];
    const float* w_C     = (const float*)d_in[7];
    const float* log_A   = (const float*)d_in[8];
    const float* D_param = (const float*)d_in[9];
    const float* dt_ptr  = (const float*)d_in[10];
    float* out = (float*)d_out;

    float* unorm = (float*)d_ws;                       // BATCH*96*1024 floats
    float* coef  = unorm + BATCH * D_MODEL * HW;       // BATCH*128*1024 floats

    hipLaunchKernelGGL(gn_kernel, dim3(BATCH * GROUPS), dim3(256), 0, stream,
                       (const float4*)u_t, gamma, beta, (float4*)unorm);
    hipLaunchKernelGGL(conv_kernel, dim3(BATCH * NCOEF), dim3(256), 0, stream,
                       (const float4*)unorm, w_delta, b_delta, w_B, w_C, dt_ptr,
                       (float4*)coef);
    hipLaunchKernelGGL(state_kernel, dim3(768), dim3(128), 0, stream,
                       (const float4*)u_t, (const float4*)s_prev, (const float4*)coef,
                       log_A, D_param, (float4*)out);
}